// Round 4
// baseline (345.980 us; speedup 1.0000x reference)
//
#include <hip/hip_runtime.h>

#define Bb 4
#define Nn 4096
#define Ee 2048
#define Dd 128
#define NL 11

typedef unsigned short u16;
typedef unsigned int u32;
typedef __attribute__((ext_vector_type(8))) short short8;
typedef __attribute__((ext_vector_type(4))) float floatx4;

__device__ __forceinline__ u16 f2bf(float f) {
    union { float f; u32 i; } v; v.f = f;
    u32 r = v.i + 0x7fffu + ((v.i >> 16) & 1u);
    return (u16)(r >> 16);
}
__device__ __forceinline__ u32 pack2(float lo, float hi) {
    union { float f; u32 i; } a, b; a.f = lo; b.f = hi;
    u32 x = a.i + 0x7fffu + ((a.i >> 16) & 1u);
    u32 y = b.i + 0x7fffu + ((b.i >> 16) & 1u);
    return (x >> 16) | (y & 0xffff0000u);
}
union S8U { u32 u[4]; short8 s; };

// ---------------- kernel 1: x0 sums over n -------------------------------
__global__ __launch_bounds__(128) void k_pool(const float* __restrict__ x,
                                              float* __restrict__ sums) {
    int b = blockIdx.x, ch = blockIdx.y, d = threadIdx.x;
    const float* p = x + ((size_t)b * Nn + (size_t)ch * 64) * Dd + d;
    float s = 0.f;
    for (int i = 0; i < 64; i++) s += p[(size_t)i * Dd];
    atomicAdd(&sums[b * Dd + d], s);
}

// ---------------- kernel 2: xe0[b][l][o] = (x0/N) . W0[l] ----------------
__global__ __launch_bounds__(128) void k_xe0(const float* __restrict__ sums,
                                             const float* __restrict__ wt,
                                             float* __restrict__ xe0) {
    int b = blockIdx.x, l = blockIdx.y, o = threadIdx.x;
    const float* w0 = wt + (size_t)l * Dd * Dd + o;
    float acc = 0.f;
    for (int d = 0; d < Dd; ++d) acc += sums[b * Dd + d] * w0[(size_t)d * Dd];
    xe0[(b * NL + l) * Dd + o] = acc * (1.0f / Nn);
}

// ------------- kernel 3: xT[b][d][n] (bf16 pairs) ------------------------
__global__ __launch_bounds__(256) void k_trx(const float* __restrict__ x,
                                             u32* __restrict__ xt) {
    int b = blockIdx.x, n0 = blockIdx.y * 32, d0 = blockIdx.z * 32;
    int t = threadIdx.x;
    __shared__ float tile[32][33];
    int r = t >> 5, c = t & 31;
#pragma unroll
    for (int i = 0; i < 4; i++)
        tile[r + 8 * i][c] = x[((size_t)b * Nn + n0 + r + 8 * i) * Dd + d0 + c];
    __syncthreads();
#pragma unroll
    for (int i = 0; i < 2; i++) {
        int idx2 = t + 256 * i;
        int dl = idx2 >> 4, cp = idx2 & 15;
        u32 v = pack2(tile[2 * cp][dl], tile[2 * cp + 1][dl]);
        xt[(size_t)(b * Dd + d0 + dl) * (Nn / 2) + (n0 >> 1) + cp] = v;
    }
}

// ---------------- bucketing: count / prefix+zero / scatter ---------------
__global__ __launch_bounds__(256) void k_count(const int* __restrict__ ord,
                                               int* __restrict__ cnt) {
    int gid = blockIdx.x * 256 + threadIdx.x;   // 0..8191
    int b = gid >> 11, e = gid & 2047;
    atomicAdd(&cnt[b * NL + ord[b * Ee + e]], 1);
}
__global__ __launch_bounds__(64) void k_prefix(const int* __restrict__ cnt,
                                               int* __restrict__ offs,
                                               int* __restrict__ idx) {
    int t = threadIdx.x;
    if (t == 0) {
        int off = 0;
        for (int i = 0; i < Bb * NL; i++) {
            offs[i] = off;
            off += (cnt[i] + 15) & ~15;
        }
    }
    for (int i = t; i < 8960; i += 64) idx[i] = 0;
}
__global__ __launch_bounds__(256) void k_scatter(const int* __restrict__ ord,
                                                 const int* __restrict__ offs,
                                                 int* __restrict__ cur,
                                                 int* __restrict__ idx) {
    int gid = blockIdx.x * 256 + threadIdx.x;
    int b = gid >> 11, e = gid & 2047;
    int bk = b * NL + ord[b * Ee + e];
    int pos = offs[bk] + atomicAdd(&cur[bk], 1);
    idx[pos] = e;
}

// ------------- kernel 4: V2E einsum -> x1e bf16 [b][e][d] ----------------
// grid (Bb, Ee/16), 256 thr (4 waves). Double-buffered LDS, 2-chunk prefetch.
__global__ __launch_bounds__(256, 2) void k_einsum(const float* __restrict__ inc,
                                                   const u32* __restrict__ xt,
                                                   const float* __restrict__ pref,
                                                   u16* __restrict__ x1e) {
    int b = blockIdx.x, et0 = blockIdx.y * 16, t = threadIdx.x;
    __shared__ u32 bufA[2][16][68];
    int ur = t >> 2, uc = t & 3;                 // staging: 64 row-pairs x 4 col4
    const float* src0 = inc + (size_t)b * Nn * Ee + et0 + 4 * uc;

    int w = t >> 6, lane = t & 63, lm = lane & 15, quad = lane >> 4;
    const u32* bp0 = xt + ((size_t)b * Dd + 32 * w + lm) * (Nn / 2);
    const u32* bp1 = bp0 + (size_t)16 * (Nn / 2);
    floatx4 acc0 = {0.f, 0.f, 0.f, 0.f}, acc1 = {0.f, 0.f, 0.f, 0.f};

    float4 pa0, pb0, pa1, pb1;
    {   // chunk 0 -> set0, chunk 1 -> set1
        const float* p = src0 + (size_t)(2 * ur) * Ee;
        pa0 = *(const float4*)p; pb0 = *(const float4*)(p + Ee);
        p = src0 + (size_t)(128 + 2 * ur) * Ee;
        pa1 = *(const float4*)p; pb1 = *(const float4*)(p + Ee);
    }
    // write chunk 0
    bufA[0][4 * uc + 0][ur] = pack2(pa0.x, pb0.x);
    bufA[0][4 * uc + 1][ur] = pack2(pa0.y, pb0.y);
    bufA[0][4 * uc + 2][ur] = pack2(pa0.z, pb0.z);
    bufA[0][4 * uc + 3][ur] = pack2(pa0.w, pb0.w);
    __syncthreads();

    for (int i = 0; i < 32; i++) {
        int nxt = (i + 2 < 32) ? i + 2 : 31;
        const float* p = src0 + (size_t)(128 * nxt + 2 * ur) * Ee;
        if ((i & 1) == 0) { pa0 = *(const float4*)p; pb0 = *(const float4*)(p + Ee); }
        else             { pa1 = *(const float4*)p; pb1 = *(const float4*)(p + Ee); }

        int cb = i & 1;
        u32 ko = (u32)(64 * i) + quad * 4;
#pragma unroll
        for (int ks = 0; ks < 4; ks++) {
            short8 A = *(const short8*)&bufA[cb][lm][ks * 16 + quad * 4];
            short8 B0 = *(const short8*)(bp0 + ko + ks * 16);
            short8 B1 = *(const short8*)(bp1 + ko + ks * 16);
            acc0 = __builtin_amdgcn_mfma_f32_16x16x32_bf16(A, B0, acc0, 0, 0, 0);
            acc1 = __builtin_amdgcn_mfma_f32_16x16x32_bf16(A, B1, acc1, 0, 0, 0);
        }
        if (i < 31) {
            int nb = 1 - cb;
            if ((i & 1) == 0) {
                bufA[nb][4 * uc + 0][ur] = pack2(pa1.x, pb1.x);
                bufA[nb][4 * uc + 1][ur] = pack2(pa1.y, pb1.y);
                bufA[nb][4 * uc + 2][ur] = pack2(pa1.z, pb1.z);
                bufA[nb][4 * uc + 3][ur] = pack2(pa1.w, pb1.w);
            } else {
                bufA[nb][4 * uc + 0][ur] = pack2(pa0.x, pb0.x);
                bufA[nb][4 * uc + 1][ur] = pack2(pa0.y, pb0.y);
                bufA[nb][4 * uc + 2][ur] = pack2(pa0.z, pb0.z);
                bufA[nb][4 * uc + 3][ur] = pack2(pa0.w, pb0.w);
            }
        }
        __syncthreads();
    }
    // store x1e (bf16), normalized. C: row(edge)=quad*4+r, col(d)=32w+lm(+16)
#pragma unroll
    for (int r = 0; r < 4; r++) {
        int e = et0 + quad * 4 + r;
        float rp = 1.0f / pref[b * Ee + e];
        u16* q = x1e + ((size_t)b * Ee + e) * Dd;
        q[32 * w + lm] = f2bf(acc0[r] * rp);
        q[32 * w + 16 + lm] = f2bf(acc1[r] * rp);
    }
}

// ------------- kernel 5: x_v via MFMA (W1[1] staged in LDS) --------------
__global__ __launch_bounds__(256) void k_xv(const float* __restrict__ x,
                                            const float* __restrict__ wt,
                                            const float* __restrict__ bt,
                                            const float* __restrict__ xe0,
                                            float* __restrict__ outv) {
    int b = blockIdx.x, n0 = blockIdx.y * 64, t = threadIdx.x;
    __shared__ u16 wT16[128][136];
    __shared__ float baseLds[128];
    const float* w11 = wt + (size_t)(NL + 1) * Dd * Dd;
    {
        int o4 = (t & 31) * 4, dr = t >> 5;
#pragma unroll
        for (int p = 0; p < 16; p++) {
            int d = dr + p * 8;
            float4 v = *(const float4*)&w11[(size_t)d * Dd + o4];
            wT16[o4 + 0][d] = f2bf(v.x);
            wT16[o4 + 1][d] = f2bf(v.y);
            wT16[o4 + 2][d] = f2bf(v.z);
            wT16[o4 + 3][d] = f2bf(v.w);
        }
        if (t < 128) baseLds[t] = xe0[(b * NL + 1) * Dd + t] + bt[Dd + t];
    }
    __syncthreads();

    int w = t >> 6, lane = t & 63, lm = lane & 15, quad = lane >> 4;
    const float* xrow = x + ((size_t)b * Nn + n0 + w * 16 + lm) * Dd;
    floatx4 acc[8];
#pragma unroll
    for (int ot = 0; ot < 8; ot++) acc[ot] = (floatx4){0.f, 0.f, 0.f, 0.f};
#pragma unroll
    for (int ks = 0; ks < 4; ks++) {
        float4 va = *(const float4*)(xrow + ks * 32 + quad * 8);
        float4 vb = *(const float4*)(xrow + ks * 32 + quad * 8 + 4);
        S8U A;
        A.u[0] = pack2(va.x, va.y); A.u[1] = pack2(va.z, va.w);
        A.u[2] = pack2(vb.x, vb.y); A.u[3] = pack2(vb.z, vb.w);
#pragma unroll
        for (int ot = 0; ot < 8; ot++) {
            short8 Bf = *(const short8*)&wT16[ot * 16 + lm][ks * 32 + quad * 8];
            acc[ot] = __builtin_amdgcn_mfma_f32_16x16x32_bf16(A.s, Bf, acc[ot], 0, 0, 0);
        }
    }
#pragma unroll
    for (int ot = 0; ot < 8; ot++) {
        float basev = baseLds[ot * 16 + lm];
#pragma unroll
        for (int r = 0; r < 4; r++)
            outv[((size_t)b * Nn + n0 + w * 16 + quad * 4 + r) * Dd + ot * 16 + lm] =
                acc[ot][r] + basev;
    }
}

// ------------- kernel 6: bucketed edge epilogue (MFMA) -------------------
// one block per (b,l): W1[l]^T staged once; x1e rows gathered as A-frags.
__global__ __launch_bounds__(256) void k_epi(const u16* __restrict__ x1e,
                                             const float* __restrict__ wt,
                                             const float* __restrict__ bt,
                                             const float* __restrict__ xe0,
                                             const int* __restrict__ cnt,
                                             const int* __restrict__ offs,
                                             const int* __restrict__ idx,
                                             float* __restrict__ oute) {
    int blk = blockIdx.x, bb = blk / NL, l = blk % NL, t = threadIdx.x;
    int cntv = cnt[blk], off = offs[blk];
    __shared__ u16 wT16[128][136];
    __shared__ float baseLds[128];
    const float* w1 = wt + (size_t)(NL + l) * Dd * Dd;
    {
        int o4 = (t & 31) * 4, dr = t >> 5;
#pragma unroll
        for (int p = 0; p < 16; p++) {
            int d = dr + p * 8;
            float4 v = *(const float4*)&w1[(size_t)d * Dd + o4];
            wT16[o4 + 0][d] = f2bf(v.x);
            wT16[o4 + 1][d] = f2bf(v.y);
            wT16[o4 + 2][d] = f2bf(v.z);
            wT16[o4 + 3][d] = f2bf(v.w);
        }
        if (t < 128) baseLds[t] = xe0[(bb * NL + l) * Dd + t] + bt[l * Dd + t];
    }
    __syncthreads();

    int w = t >> 6, lane = t & 63, lm = lane & 15, quad = lane >> 4;
    int ntile = (cntv + 15) >> 4;
    for (int j = w; j < ntile; j += 4) {
        int rA = idx[off + j * 16 + lm];
        int4 rid = *(const int4*)&idx[off + j * 16 + quad * 4];
        const u16* ap = x1e + ((size_t)bb * Ee + rA) * Dd;
        floatx4 acc[8];
#pragma unroll
        for (int ot = 0; ot < 8; ot++) acc[ot] = (floatx4){0.f, 0.f, 0.f, 0.f};
#pragma unroll
        for (int ks = 0; ks < 4; ks++) {
            short8 A = *(const short8*)(ap + ks * 32 + quad * 8);
#pragma unroll
            for (int ot = 0; ot < 8; ot++) {
                short8 Bf = *(const short8*)&wT16[ot * 16 + lm][ks * 32 + quad * 8];
                acc[ot] = __builtin_amdgcn_mfma_f32_16x16x32_bf16(A, Bf, acc[ot], 0, 0, 0);
            }
        }
        int rowbase = j * 16 + quad * 4;
#pragma unroll
        for (int ot = 0; ot < 8; ot++) {
            float basev = baseLds[ot * 16 + lm];
#pragma unroll
            for (int r = 0; r < 4; r++) {
                if (rowbase + r < cntv) {
                    int e = ((const int*)&rid)[r];
                    oute[((size_t)bb * Ee + e) * Dd + ot * 16 + lm] = acc[ot][r] + basev;
                }
            }
        }
    }
}

extern "C" void kernel_launch(void* const* d_in, const int* in_sizes, int n_in,
                              void* d_out, int out_size, void* d_ws,
                              size_t ws_size, hipStream_t stream) {
    const float* x    = (const float*)d_in[0];
    const float* inc  = (const float*)d_in[1];
    const int*   ord  = (const int*)d_in[2];
    const float* pref = (const float*)d_in[3];
    const float* wt   = (const float*)d_in[7];
    const float* bt   = (const float*)d_in[8];

    float* outv = (float*)d_out;
    float* oute = outv + (size_t)Bb * Nn * Dd;

    float* ws   = (float*)d_ws;
    float* sums = ws;                          // 512
    float* xe0  = ws + 512;                    // 5632
    int*   cnt  = (int*)(ws + 6144);           // 44
    int*   offs = (int*)(ws + 6192);           // 44
    int*   cur  = (int*)(ws + 6240);           // 44
    u32*   xt   = (u32*)(ws + 8192);           // 1 Mi u32 (4 MB)
    int*   idx  = (int*)(ws + 8192 + 1048576); // 8960 ints
    u16*   x1e  = (u16*)(ws + 8192 + 1048576 + 8960);  // 1 Mi u16 (2 MB)

    hipMemsetAsync(d_ws, 0, 6288 * sizeof(float), stream);
    k_pool<<<dim3(Bb, 64), 128, 0, stream>>>(x, sums);
    k_xe0<<<dim3(Bb, NL), 128, 0, stream>>>(sums, wt, xe0);
    k_trx<<<dim3(Bb, Nn / 32, Dd / 32), 256, 0, stream>>>(x, xt);
    k_count<<<32, 256, 0, stream>>>(ord, cnt);
    k_prefix<<<1, 64, 0, stream>>>(cnt, offs, idx);
    k_scatter<<<32, 256, 0, stream>>>(ord, offs, cur, idx);
    k_einsum<<<dim3(Bb, Ee / 16), 256, 0, stream>>>(inc, xt, pref, x1e);
    k_xv<<<dim3(Bb, Nn / 64), 256, 0, stream>>>(x, wt, bt, xe0, outv);
    k_epi<<<Bb * NL, 256, 0, stream>>>(x1e, wt, bt, xe0, cnt, offs, idx, oute);
}

// Round 5
// 320.389 us; speedup vs baseline: 1.0799x; 1.0799x over previous
//
#include <hip/hip_runtime.h>

#define Bb 4
#define Nn 4096
#define Ee 2048
#define Dd 128
#define NL 11
#define NTMAX 560

typedef unsigned short u16;
typedef unsigned int u32;
typedef __attribute__((ext_vector_type(8))) short short8;
typedef __attribute__((ext_vector_type(4))) float floatx4;

__device__ __forceinline__ u16 f2bf(float f) {
    union { float f; u32 i; } v; v.f = f;
    u32 r = v.i + 0x7fffu + ((v.i >> 16) & 1u);
    return (u16)(r >> 16);
}
__device__ __forceinline__ u32 pack2(float lo, float hi) {
    union { float f; u32 i; } a, b; a.f = lo; b.f = hi;
    u32 x = a.i + 0x7fffu + ((a.i >> 16) & 1u);
    u32 y = b.i + 0x7fffu + ((b.i >> 16) & 1u);
    return (x >> 16) | (y & 0xffff0000u);
}
union S8U { u32 u[4]; short8 s; };

// ---- kernel 1: transpose x -> xt (bf16 pairs, d-major) + column sums ------
__global__ __launch_bounds__(256) void k_trx(const float* __restrict__ x,
                                             u32* __restrict__ xt,
                                             float* __restrict__ sums) {
    int b = blockIdx.x, n0 = blockIdx.y * 32, d0 = blockIdx.z * 32;
    int t = threadIdx.x;
    __shared__ float tile[32][33];
    int r = t >> 5, c = t & 31;
#pragma unroll
    for (int i = 0; i < 4; i++)
        tile[r + 8 * i][c] = x[((size_t)b * Nn + n0 + r + 8 * i) * Dd + d0 + c];
    __syncthreads();
#pragma unroll
    for (int i = 0; i < 2; i++) {
        int idx2 = t + 256 * i;
        int dl = idx2 >> 4, cp = idx2 & 15;
        u32 v = pack2(tile[2 * cp][dl], tile[2 * cp + 1][dl]);
        xt[(size_t)(b * Dd + d0 + dl) * (Nn / 2) + (n0 >> 1) + cp] = v;
    }
    if (t < 32) {
        float s = 0.f;
#pragma unroll
        for (int rr = 0; rr < 32; rr++) s += tile[rr][t];
        atomicAdd(&sums[b * Dd + d0 + t], s);
    }
}

// ---- kernel 2: xe0b[b][l][o] = (x0/N).W0[l] + b_table[l] ------------------
__global__ __launch_bounds__(128) void k_xe0(const float* __restrict__ sums,
                                             const float* __restrict__ wt,
                                             const float* __restrict__ bt,
                                             float* __restrict__ xe0b) {
    int b = blockIdx.x, l = blockIdx.y, o = threadIdx.x;
    const float* w0 = wt + (size_t)l * Dd * Dd + o;
    float acc = 0.f;
    for (int d = 0; d < Dd; ++d) acc += sums[b * Dd + d] * w0[(size_t)d * Dd];
    xe0b[(b * NL + l) * Dd + o] = acc * (1.0f / Nn) + bt[l * Dd + o];
}

// ---- kernel 3: wt1T[l][o][d] = bf16(W1[l][d][o])  (B-frag-ready) ----------
__global__ __launch_bounds__(256) void k_trw(const float* __restrict__ wt,
                                             u32* __restrict__ wt1T) {
    int l = blockIdx.x, d0 = blockIdx.y * 32, o0 = blockIdx.z * 32;
    int t = threadIdx.x;
    __shared__ float tile[32][33];
    const float* w1 = wt + (size_t)(NL + l) * Dd * Dd;
    int r = t >> 5, c = t & 31;
#pragma unroll
    for (int i = 0; i < 4; i++)
        tile[r + 8 * i][c] = w1[(size_t)(d0 + r + 8 * i) * Dd + o0 + c];
    __syncthreads();
#pragma unroll
    for (int i = 0; i < 2; i++) {
        int idx2 = t + 256 * i;
        int ol = idx2 >> 4, dp = idx2 & 15;
        u32 v = pack2(tile[2 * dp][ol], tile[2 * dp + 1][ol]);
        wt1T[(size_t)(l * Dd + o0 + ol) * (Dd / 2) + (d0 >> 1) + dp] = v;
    }
}

// ---- bucketing -----------------------------------------------------------
__global__ __launch_bounds__(256) void k_count(const int* __restrict__ ord,
                                               int* __restrict__ cnt) {
    int gid = blockIdx.x * 256 + threadIdx.x;
    int b = gid >> 11, e = gid & 2047;
    atomicAdd(&cnt[b * NL + ord[b * Ee + e]], 1);
}
__global__ __launch_bounds__(64) void k_prefix(const int* __restrict__ cnt,
                                               int* __restrict__ offs,
                                               int* __restrict__ idx,
                                               int* __restrict__ tilemap) {
    int t = threadIdx.x;
    if (t == 0) {
        int off = 0, pos = 0;
        for (int i = 0; i < Bb * NL; i++) {
            offs[i] = off;
            int al = (cnt[i] + 15) & ~15;
            off += al;
            for (int j = 0; j < (al >> 4); j++) tilemap[pos++] = (i << 16) | j;
        }
        for (; pos < NTMAX; pos++) tilemap[pos] = -1;
    }
    for (int i = t; i < 8960; i += 64) idx[i] = 0;
}
__global__ __launch_bounds__(256) void k_scatter(const int* __restrict__ ord,
                                                 const int* __restrict__ offs,
                                                 int* __restrict__ cur,
                                                 int* __restrict__ idx) {
    int gid = blockIdx.x * 256 + threadIdx.x;
    int b = gid >> 11, e = gid & 2047;
    int bk = b * NL + ord[b * Ee + e];
    int pos = offs[bk] + atomicAdd(&cur[bk], 1);
    idx[pos] = e;
}

// ---- kernel 4: V2E einsum partials (n-split), fp32 out --------------------
// grid (Bb, Ee/32, 2), 256 thr. 32 edges x 128 d x 2048 n per block.
__global__ __launch_bounds__(256) void k_einsum(const float* __restrict__ inc,
                                                const u32* __restrict__ xt,
                                                float* __restrict__ x1p) {
    int b = blockIdx.x, et0 = blockIdx.y * 32, s = blockIdx.z, t = threadIdx.x;
    int nbase = s * 2048;
    __shared__ u32 bufA[2][32][68];
    const float* src = inc + ((size_t)b * Nn + nbase) * Ee + et0;
    int pr0 = t >> 3, c4 = t & 7;        // task rows 2*pr0, 2*pr0+1 (+64 for task1)
    int pr1 = pr0 + 32;

    int w = t >> 6, lane = t & 63, lm = lane & 15, quad = lane >> 4;
    const u32* bp0 = xt + ((size_t)b * Dd + w * 32 + lm) * (Nn / 2) + (nbase >> 1);
    const u32* bp1 = bp0 + (size_t)16 * (Nn / 2);
    floatx4 a00 = {0.f,0.f,0.f,0.f}, a01 = {0.f,0.f,0.f,0.f};
    floatx4 a10 = {0.f,0.f,0.f,0.f}, a11 = {0.f,0.f,0.f,0.f};

    float4 sA[4], sB[4];
    auto ldchunk = [&](int ci, float4* st) {
        const float* p0 = src + (size_t)(ci * 128 + 2 * pr0) * Ee + 4 * c4;
        st[0] = *(const float4*)p0;
        st[1] = *(const float4*)(p0 + Ee);
        const float* p1 = src + (size_t)(ci * 128 + 2 * pr1) * Ee + 4 * c4;
        st[2] = *(const float4*)p1;
        st[3] = *(const float4*)(p1 + Ee);
    };
    auto wrchunk = [&](int cb, const float4* st) {
        bufA[cb][4 * c4 + 0][pr0] = pack2(st[0].x, st[1].x);
        bufA[cb][4 * c4 + 1][pr0] = pack2(st[0].y, st[1].y);
        bufA[cb][4 * c4 + 2][pr0] = pack2(st[0].z, st[1].z);
        bufA[cb][4 * c4 + 3][pr0] = pack2(st[0].w, st[1].w);
        bufA[cb][4 * c4 + 0][pr1] = pack2(st[2].x, st[3].x);
        bufA[cb][4 * c4 + 1][pr1] = pack2(st[2].y, st[3].y);
        bufA[cb][4 * c4 + 2][pr1] = pack2(st[2].z, st[3].z);
        bufA[cb][4 * c4 + 3][pr1] = pack2(st[2].w, st[3].w);
    };
    ldchunk(0, sA);
    ldchunk(1, sB);
    wrchunk(0, sA);
    __syncthreads();

    for (int i = 0; i < 16; i++) {
        int cb = i & 1;
        int nc = (i + 2 < 16) ? i + 2 : 15;
        if (cb == 0) ldchunk(nc, sA); else ldchunk(nc, sB);
        int ko = i * 64;
#pragma unroll
        for (int ks = 0; ks < 4; ks++) {
            short8 A0 = *(const short8*)&bufA[cb][lm][ks * 16 + quad * 4];
            short8 A1 = *(const short8*)&bufA[cb][16 + lm][ks * 16 + quad * 4];
            short8 B0 = *(const short8*)(bp0 + ko + ks * 16 + quad * 4);
            short8 B1 = *(const short8*)(bp1 + ko + ks * 16 + quad * 4);
            a00 = __builtin_amdgcn_mfma_f32_16x16x32_bf16(A0, B0, a00, 0, 0, 0);
            a01 = __builtin_amdgcn_mfma_f32_16x16x32_bf16(A0, B1, a01, 0, 0, 0);
            a10 = __builtin_amdgcn_mfma_f32_16x16x32_bf16(A1, B0, a10, 0, 0, 0);
            a11 = __builtin_amdgcn_mfma_f32_16x16x32_bf16(A1, B1, a11, 0, 0, 0);
        }
        if (i < 15) { if (cb == 0) wrchunk(1, sB); else wrchunk(0, sA); }
        __syncthreads();
    }

    int db = w * 32 + lm;
    float* base = x1p + ((size_t)(s * Bb + b) * Ee) * Dd;
#pragma unroll
    for (int r = 0; r < 4; r++) {
        float* q0 = base + (size_t)(et0 + quad * 4 + r) * Dd;
        q0[db] = a00[r];
        q0[db + 16] = a01[r];
        float* q1 = base + (size_t)(et0 + 16 + quad * 4 + r) * Dd;
        q1[db] = a10[r];
        q1[db + 16] = a11[r];
    }
}

// ---- kernel 5: x_v via MFMA, no LDS (B-frags from wt1T, L2-hot) -----------
__global__ __launch_bounds__(256) void k_xv(const float* __restrict__ x,
                                            const u32* __restrict__ wt1T,
                                            const float* __restrict__ xe0b,
                                            float* __restrict__ outv) {
    int b = blockIdx.x, n0 = blockIdx.y * 64, t = threadIdx.x;
    int w = t >> 6, lane = t & 63, lm = lane & 15, quad = lane >> 4;
    const float* xrow = x + ((size_t)b * Nn + n0 + w * 16 + lm) * Dd;
    const u32* wrow = wt1T + (size_t)1 * Dd * (Dd / 2);   // l = 1
    floatx4 acc[8];
#pragma unroll
    for (int ot = 0; ot < 8; ot++) acc[ot] = (floatx4){0.f, 0.f, 0.f, 0.f};
#pragma unroll
    for (int ks = 0; ks < 4; ks++) {
        float4 va = *(const float4*)(xrow + ks * 32 + quad * 8);
        float4 vb = *(const float4*)(xrow + ks * 32 + quad * 8 + 4);
        S8U A;
        A.u[0] = pack2(va.x, va.y); A.u[1] = pack2(va.z, va.w);
        A.u[2] = pack2(vb.x, vb.y); A.u[3] = pack2(vb.z, vb.w);
#pragma unroll
        for (int ot = 0; ot < 8; ot++) {
            short8 Bf = *(const short8*)(wrow + (size_t)(ot * 16 + lm) * (Dd / 2) +
                                         ks * 16 + quad * 4);
            acc[ot] = __builtin_amdgcn_mfma_f32_16x16x32_bf16(A.s, Bf, acc[ot], 0, 0, 0);
        }
    }
#pragma unroll
    for (int ot = 0; ot < 8; ot++) {
        float basev = xe0b[(b * NL + 1) * Dd + ot * 16 + lm];
#pragma unroll
        for (int r = 0; r < 4; r++)
            outv[((size_t)b * Nn + n0 + w * 16 + quad * 4 + r) * Dd + ot * 16 + lm] =
                acc[ot][r] + basev;
    }
}

// ---- kernel 6: bucketed epilogue, 1 wave = one 16-edge tile, no LDS -------
__global__ __launch_bounds__(256) void k_epi(const float* __restrict__ x1p,
                                             const float* __restrict__ pref,
                                             const u32* __restrict__ wt1T,
                                             const float* __restrict__ xe0b,
                                             const int* __restrict__ cnt,
                                             const int* __restrict__ offs,
                                             const int* __restrict__ idx,
                                             const int* __restrict__ tilemap,
                                             float* __restrict__ oute) {
    int t = threadIdx.x, w = t >> 6, lane = t & 63, lm = lane & 15, quad = lane >> 4;
    int ent = tilemap[blockIdx.x * 4 + w];
    if (ent < 0) return;
    int bk = ent >> 16, j = ent & 0xffff;
    int bb = bk / NL, l = bk % NL;
    int off = offs[bk], cntv = cnt[bk];
    int eA = idx[off + j * 16 + lm];
    float rp = 1.0f / pref[bb * Ee + eA];
    const float* p0 = x1p + ((size_t)bb * Ee + eA) * Dd;
    const float* p1 = p0 + (size_t)Bb * Ee * Dd;
    const u32* wrow = wt1T + (size_t)l * Dd * (Dd / 2);
    floatx4 acc[8];
#pragma unroll
    for (int ot = 0; ot < 8; ot++) acc[ot] = (floatx4){0.f, 0.f, 0.f, 0.f};
#pragma unroll
    for (int ks = 0; ks < 4; ks++) {
        int d0 = ks * 32 + quad * 8;
        float4 u0 = *(const float4*)(p0 + d0);
        float4 u1 = *(const float4*)(p0 + d0 + 4);
        float4 v0 = *(const float4*)(p1 + d0);
        float4 v1 = *(const float4*)(p1 + d0 + 4);
        S8U A;
        A.u[0] = pack2((u0.x + v0.x) * rp, (u0.y + v0.y) * rp);
        A.u[1] = pack2((u0.z + v0.z) * rp, (u0.w + v0.w) * rp);
        A.u[2] = pack2((u1.x + v1.x) * rp, (u1.y + v1.y) * rp);
        A.u[3] = pack2((u1.z + v1.z) * rp, (u1.w + v1.w) * rp);
#pragma unroll
        for (int ot = 0; ot < 8; ot++) {
            short8 Bf = *(const short8*)(wrow + (size_t)(ot * 16 + lm) * (Dd / 2) +
                                         ks * 16 + quad * 4);
            acc[ot] = __builtin_amdgcn_mfma_f32_16x16x32_bf16(A.s, Bf, acc[ot], 0, 0, 0);
        }
    }
    int4 rid = *(const int4*)&idx[off + j * 16 + quad * 4];
    int rowbase = j * 16 + quad * 4;
#pragma unroll
    for (int ot = 0; ot < 8; ot++) {
        float basev = xe0b[(bb * NL + l) * Dd + ot * 16 + lm];
#pragma unroll
        for (int r = 0; r < 4; r++) {
            if (rowbase + r < cntv) {
                int e = ((const int*)&rid)[r];
                oute[((size_t)bb * Ee + e) * Dd + ot * 16 + lm] = acc[ot][r] + basev;
            }
        }
    }
}

extern "C" void kernel_launch(void* const* d_in, const int* in_sizes, int n_in,
                              void* d_out, int out_size, void* d_ws,
                              size_t ws_size, hipStream_t stream) {
    const float* x    = (const float*)d_in[0];
    const float* inc  = (const float*)d_in[1];
    const int*   ord  = (const int*)d_in[2];
    const float* pref = (const float*)d_in[3];
    const float* wt   = (const float*)d_in[7];
    const float* bt   = (const float*)d_in[8];

    float* outv = (float*)d_out;
    float* oute = outv + (size_t)Bb * Nn * Dd;

    float* ws      = (float*)d_ws;
    float* sums    = ws;                        // 512
    float* xe0b    = ws + 512;                  // 5632
    int*   cnt     = (int*)(ws + 6144);         // 44
    int*   offs    = (int*)(ws + 6192);         // 44
    int*   cur     = (int*)(ws + 6240);         // 44
    int*   tilemap = (int*)(ws + 6288);         // 560
    u32*   xt      = (u32*)(ws + 8192);         // 1048576 u32 (4 MB)
    u32*   wt1T    = (u32*)(ws + 8192 + 1048576);          // 90112 u32
    int*   idx     = (int*)(ws + 8192 + 1048576 + 90112);  // 8960
    float* x1p     = ws + 8192 + 1048576 + 90112 + 8960;   // 2097152 f (8 MB)

    hipMemsetAsync(d_ws, 0, 6848 * sizeof(float), stream);
    k_trx<<<dim3(Bb, Nn / 32, Dd / 32), 256, 0, stream>>>(x, xt, sums);
    k_xe0<<<dim3(Bb, NL), 128, 0, stream>>>(sums, wt, bt, xe0b);
    k_trw<<<dim3(NL, 4, 4), 256, 0, stream>>>(wt, wt1T);
    k_count<<<32, 256, 0, stream>>>(ord, cnt);
    k_prefix<<<1, 64, 0, stream>>>(cnt, offs, idx, tilemap);
    k_scatter<<<32, 256, 0, stream>>>(ord, offs, cur, idx);
    k_einsum<<<dim3(Bb, Ee / 32, 2), 256, 0, stream>>>(inc, xt, x1p);
    k_xv<<<dim3(Bb, Nn / 64), 256, 0, stream>>>(x, wt1T, xe0b, outv);
    k_epi<<<NTMAX / 4, 256, 0, stream>>>(x1p, pref, wt1T, xe0b, cnt, offs, idx,
                                         tilemap, oute);
}